// Round 7
// baseline (15876.561 us; speedup 1.0000x reference)
//
#include <hip/hip_runtime.h>
#include <stddef.h>
#include <stdint.h>

// Elman RNN: out[t,b,u] = h_t = tanh(x_t @ Wx + h_{t-1} @ Wh + bias)
// B=128, T=512, D=128, U=512. Output [T, B, U] float32.
//
// pgemm (f16 dot2): P = x@Wx + bias -> d_out. (~15 us)
// rnn: TWO WGs per batch row (256 WGs = full chip), column-split:
//   WG half owns output cols [half*256, half*256+256). Its Wh slice
//   (512 k x 256 cols f16) = 128 u32/thread -> FULLY register-resident;
//   zero W re-streaming (round 6 was LDS-throughput-bound on 128KB/step).
//   Per step each WG computes its h half; halves exchange h via packed-f16
//   buffer in d_ws with device-scope atomics + per-row flag counter
//   (release post / acquire poll). Poll runs only on the 4 waves that
//   consume partner data, overlapped with the local waves' dot phase.
//   Double-buffered by t parity. Flags memset per launch (capture-safe).

constexpr int B = 128;
constexpr int T = 512;
constexpr int D = 128;
constexpr int U = 512;

typedef _Float16 f16;
typedef _Float16 f16x2 __attribute__((ext_vector_type(2)));
typedef __fp16   fp16x2 __attribute__((ext_vector_type(2)));
typedef unsigned int u32;
typedef u32 u32x16 __attribute__((ext_vector_type(16)));

union U32H2 { u32 u; f16x2 h; fp16x2 p; };

static __device__ __forceinline__ u32 pk(float a, float b) {
    U32H2 c; c.p = __builtin_amdgcn_cvt_pkrtz(a, b); return c.u;
}

#if __has_builtin(__builtin_amdgcn_fdot2)
static __device__ __forceinline__ float fdot2(u32 a, u32 b, float c) {
    U32H2 x, y; x.u = a; y.u = b;
    return __builtin_amdgcn_fdot2(x.h, y.h, c, false);
}
#else
static __device__ __forceinline__ float fdot2(u32 a, u32 b, float c) {
    U32H2 x, y; x.u = a; y.u = b;
    return c + (float)x.h.x * (float)y.h.x + (float)x.h.y * (float)y.h.y;
}
#endif

static __device__ __forceinline__ float fast_tanh(float x) {
    float e = __expf(2.0f * x);
    return 1.0f - 2.0f * __builtin_amdgcn_rcpf(e + 1.0f);
}

// ---------------------------------------------------------------------------
// Kernel 1: P = x @ Wx + bias  (M=T*B, K=D=128 one-shot, N=U) — f16 dot2
// ---------------------------------------------------------------------------
__global__ __launch_bounds__(256) void pgemm_kernel(
    const float* __restrict__ x,     // [B, T, D]
    const float* __restrict__ Wx,    // [D, U]
    const float* __restrict__ bias,  // [U]
    float* __restrict__ P)           // [T*B, U]  (== d_out)
{
    __shared__ u32 xs[128][66];      // [row][k-pair]   (+2 pad)
    __shared__ u32 ws[64][132];      // [k-pair][col]   (+4 pad)

    const int rb  = blockIdx.x;
    const int cb  = blockIdx.y;
    const int tid = threadIdx.x;
    const int tr  = tid >> 4;
    const int tcc = tid & 15;

    const float4* x4 = (const float4*)x;
#pragma unroll
    for (int l = 0; l < 16; ++l) {
        int idx = tid + l * 256;
        int r   = idx >> 5;
        int q   = idx & 31;
        int m   = rb * 128 + r;
        int b_  = m & 127;
        int t_  = m >> 7;
        float4 v = x4[((size_t)b_ * T + t_) * 32 + q];
        xs[r][2 * q]     = pk(v.x, v.y);
        xs[r][2 * q + 1] = pk(v.z, v.w);
    }
    const float4* W4 = (const float4*)Wx;
#pragma unroll
    for (int l = 0; l < 8; ++l) {
        int idx = tid + l * 256;
        int kp  = idx >> 5;
        int q   = idx & 31;
        float4 a = W4[(size_t)(2 * kp)     * 128 + cb * 32 + q];
        float4 c = W4[(size_t)(2 * kp + 1) * 128 + cb * 32 + q];
        uint4 w;
        w.x = pk(a.x, c.x); w.y = pk(a.y, c.y);
        w.z = pk(a.z, c.z); w.w = pk(a.w, c.w);
        *(uint4*)&ws[kp][4 * q] = w;
    }
    __syncthreads();

    float acc[8][8];
#pragma unroll
    for (int i = 0; i < 8; ++i)
#pragma unroll
        for (int j = 0; j < 8; ++j) acc[i][j] = 0.f;

#pragma unroll 2
    for (int kp = 0; kp < 64; ++kp) {
        u32 xv[8], wv[8];
#pragma unroll
        for (int i = 0; i < 8; ++i) xv[i] = xs[tr + 16 * i][kp];
#pragma unroll
        for (int j = 0; j < 8; ++j) wv[j] = ws[kp][tcc + 16 * j];
#pragma unroll
        for (int i = 0; i < 8; ++i)
#pragma unroll
            for (int j = 0; j < 8; ++j)
                acc[i][j] = fdot2(xv[i], wv[j], acc[i][j]);
    }

#pragma unroll
    for (int j = 0; j < 8; ++j) {
        int c    = cb * 128 + tcc + 16 * j;
        float bv = bias[c];
#pragma unroll
        for (int i = 0; i < 8; ++i) {
            int m = rb * 128 + tr + 16 * i;
            P[(size_t)m * U + c] = acc[i][j] + bv;
        }
    }
}

// ---------------------------------------------------------------------------
// Kernel 2: recurrence. 256 WGs (512 thr): bid -> (b, half).
//   half = (bid>>3)&1, b = (bid&7)*16 + (bid>>4); partner = bid^8 (same XCD
//   under round-robin %8 — latency hint only, correctness via agent atomics).
//   tk = tid>>4 (0..31) owns k-pairs [8tk, 8tk+8); tc = tid&15 owns cols
//   cbase + tc + 16j. W = 8 named u32x16 (128 VGPR words), full slice.
// ---------------------------------------------------------------------------
__global__ __launch_bounds__(512)
__attribute__((amdgpu_waves_per_eu(2, 2)))
void rnn_kernel(
    const float* __restrict__ Wh,    // [U, U] f32
    float* __restrict__ out,         // [T*B, U]; P on entry, h on exit
    u32* __restrict__ flags,         // [B] step counters (zeroed per launch)
    u32* __restrict__ hx)            // [B][2 parity][2 half][128] packed f16
{
    __shared__ __align__(16) u32 part[8 * 33 * 16];  // 16.9 KB, conflict-free
    __shared__ __align__(16) u32 hbuf[128];          // local h half, packed f16

    const int tid   = threadIdx.x;
    const int bid   = blockIdx.x;
    const int half  = (bid >> 3) & 1;
    const int b     = (bid & 7) * 16 + (bid >> 4);
    const int tk    = tid >> 4;          // 0..31
    const int tc    = tid & 15;          // 0..15
    const int ktk   = tk & 15;           // slice index within a half
    const bool is_local = ((tk >> 4) == half);
    const int cbase = half * 256;

    // ---- W slice: pairs p = 8tk+pi (k = 2p, 2p+1), cols cbase+tc+16j ----
    u32x16 W0, W1, W2, W3, W4, W5, W6, W7;
#define LOADW(pi)                                                         \
    {                                                                     \
        const float* r0 = Wh + (size_t)(16 * tk + 2 * (pi)) * U + cbase + tc; \
        _Pragma("unroll")                                                 \
        for (int j = 0; j < 16; ++j)                                      \
            W##pi[j] = pk(r0[16 * j], r0[U + 16 * j]);                    \
    }
    LOADW(0) LOADW(1) LOADW(2) LOADW(3)
    LOADW(4) LOADW(5) LOADW(6) LOADW(7)
#undef LOADW

    if (tid < 128) hbuf[tid] = 0u;       // h_0 = 0 (local half)
    __syncthreads();

    u32 ph[8];                            // partner h pairs (regs)
#pragma unroll
    for (int i = 0; i < 8; ++i) ph[i] = 0u;

    u32* flagp  = flags + b;
    float* outb = out + (size_t)b * U;

    // P prefetch for t=0 (own half)
    float pv = 0.f;
    if (tid < 256) pv = outb[cbase + tid];

    for (int t = 0; t < T; ++t) {
        // partner h_{t-1}: poll + load (only the 4 waves that consume it;
        // overlaps the local waves' dot phase)
        if (t > 0 && !is_local) {
            const u32 target = 2u * (u32)t;
            while (__hip_atomic_load(flagp, __ATOMIC_ACQUIRE,
                                     __HIP_MEMORY_SCOPE_AGENT) < target)
                __builtin_amdgcn_s_sleep(2);
            const u32* src = hx + (((size_t)b * 2 + ((t - 1) & 1)) * 2
                                   + (1 - half)) * 128 + 8 * ktk;
#pragma unroll
            for (int i = 0; i < 8; ++i)
                ph[i] = __hip_atomic_load(src + i, __ATOMIC_RELAXED,
                                          __HIP_MEMORY_SCOPE_AGENT);
        }

        // h input pairs for this thread's k-slice
        u32 hp[8];
        if (is_local) {
            const uint4* hb4 = (const uint4*)hbuf;
            uint4 a = hb4[2 * ktk];
            uint4 c = hb4[2 * ktk + 1];
            hp[0] = a.x; hp[1] = a.y; hp[2] = a.z; hp[3] = a.w;
            hp[4] = c.x; hp[5] = c.y; hp[6] = c.z; hp[7] = c.w;
        } else {
#pragma unroll
            for (int i = 0; i < 8; ++i) hp[i] = ph[i];
        }

        float acc[16];
#pragma unroll
        for (int j = 0; j < 16; ++j) acc[j] = 0.f;

#define DOT16(hq, Wq)                                                     \
        {                                                                 \
            u32 hq_ = (hq);                                               \
            _Pragma("unroll")                                             \
            for (int j = 0; j < 16; ++j)                                  \
                acc[j] = fdot2(hq_, Wq[j], acc[j]);                       \
        }
        DOT16(hp[0], W0) DOT16(hp[1], W1) DOT16(hp[2], W2) DOT16(hp[3], W3)
        DOT16(hp[4], W4) DOT16(hp[5], W5) DOT16(hp[6], W6) DOT16(hp[7], W7)
#undef DOT16

        // partials: pack cols (j, j+8); [8][33][16] layout -> <=2-way banks
#pragma unroll
        for (int j = 0; j < 8; ++j)
            part[(j * 33 + tk) * 16 + tc] = pk(acc[j], acc[j + 8]);

        __syncthreads();   // partials visible

        float nv = 0.f;
        if (tid < 256) {
            const int r   = tid;
            const int tcr = r & 15;
            const int jg  = (r >> 4) & 7;
            const int hi  = r >> 7;
            float s = pv;
#pragma unroll
            for (int i = 0; i < 32; ++i) {
                U32H2 w; w.u = part[(jg * 33 + i) * 16 + tcr];
                s += hi ? (float)w.h.y : (float)w.h.x;
            }
            float hv = fast_tanh(s);
            float* prow = outb + (size_t)t * (B * U);
            prow[cbase + r] = hv;                       // final output (f32)
            if (t + 1 < T) nv = prow[B * U + cbase + r]; // prefetch next P
            float ho = __shfl_xor(hv, 1);
            if (!(r & 1)) {
                u32 u = pk(hv, ho);
                hbuf[r >> 1] = u;                        // local state
                u32* dst = hx + (((size_t)b * 2 + (t & 1)) * 2 + half) * 128
                           + (r >> 1);
                __hip_atomic_store(dst, u, __ATOMIC_RELAXED,
                                   __HIP_MEMORY_SCOPE_AGENT);
            }
            __threadfence();   // hx stores visible before flag post
        }
        __syncthreads();       // hbuf/part reuse safe; stores drained

        if (t + 1 < T && tid == 0)
            __hip_atomic_fetch_add(flagp, 1u, __ATOMIC_RELEASE,
                                   __HIP_MEMORY_SCOPE_AGENT);
        pv = nv;
    }
}

// ---------------------------------------------------------------------------
extern "C" void kernel_launch(void* const* d_in, const int* in_sizes, int n_in,
                              void* d_out, int out_size, void* d_ws, size_t ws_size,
                              hipStream_t stream)
{
    (void)in_sizes; (void)n_in; (void)out_size; (void)ws_size;
    const float* x    = (const float*)d_in[0];  // [B, T, D]
    const float* Wx   = (const float*)d_in[1];  // [D, U]
    const float* Wh   = (const float*)d_in[2];  // [U, U]
    const float* bias = (const float*)d_in[3];  // [U]
    float* out = (float*)d_out;                 // [T, B, U]

    u32* flags = (u32*)d_ws;                    // 512 B (B=128 counters)
    u32* hx    = (u32*)((char*)d_ws + 512);     // 256 KB exchange buffer

    // reset flags every launch (graph-capture-safe async memset)
    hipMemsetAsync(d_ws, 0, 512, stream);

    pgemm_kernel<<<dim3((T * B) / 128, U / 128), 256, 0, stream>>>(x, Wx, bias, out);
    rnn_kernel<<<2 * B, 512, 0, stream>>>(Wh, out, flags, hx);
}

// Round 8
// 1650.115 us; speedup vs baseline: 9.6215x; 9.6215x over previous
//
#include <hip/hip_runtime.h>
#include <stddef.h>
#include <stdint.h>

// Elman RNN: out[t,b,u] = h_t = tanh(x_t @ Wx + h_{t-1} @ Wh + bias)
// B=128, T=512, D=128, U=512. Output [T, B, U] float32.
//
// pgemm (f16 dot2): P = x@Wx + bias -> d_out. (~15 us)
// rnn: ONE WG (512 thr) per batch row (cross-WG sync measured at 31 us/step
//   in round 7 -> dead; intra-WG is the only viable structure).
//   tk = tid>>5 owns 16 contiguous k-pairs; tc = tid&31 owns 16 cols.
//   W pairs 0..11 in 12 named u32x16 regs (192 words, AGPR-backed),
//   pairs 12..15 in LDS (128 KB, lane-major uint4).
//   Round-8 changes vs round-6 (973 us):
//     * wave pre-reduce via shfl_xor(32): partial rows 16 -> 8
//     * part/hbuf double-buffered by t-parity
//     * next-step W-LDS batches issued before the barrier window so the
//       128KB/step W stream drains under partial-write + reduce phases

constexpr int B = 128;
constexpr int T = 512;
constexpr int D = 128;
constexpr int U = 512;

typedef _Float16 f16;
typedef _Float16 f16x2 __attribute__((ext_vector_type(2)));
typedef __fp16   fp16x2 __attribute__((ext_vector_type(2)));
typedef unsigned int u32;
typedef u32 u32x16 __attribute__((ext_vector_type(16)));

union U32H2 { u32 u; f16x2 h; fp16x2 p; };

static __device__ __forceinline__ u32 pk(float a, float b) {
    U32H2 c; c.p = __builtin_amdgcn_cvt_pkrtz(a, b); return c.u;
}

#if __has_builtin(__builtin_amdgcn_fdot2)
static __device__ __forceinline__ float fdot2(u32 a, u32 b, float c) {
    U32H2 x, y; x.u = a; y.u = b;
    return __builtin_amdgcn_fdot2(x.h, y.h, c, false);
}
#else
static __device__ __forceinline__ float fdot2(u32 a, u32 b, float c) {
    U32H2 x, y; x.u = a; y.u = b;
    return c + (float)x.h.x * (float)y.h.x + (float)x.h.y * (float)y.h.y;
}
#endif

static __device__ __forceinline__ float fast_tanh(float x) {
    float e = __expf(2.0f * x);
    return 1.0f - 2.0f * __builtin_amdgcn_rcpf(e + 1.0f);
}

// ---------------------------------------------------------------------------
// Kernel 1: P = x @ Wx + bias  (M=T*B, K=D=128 one-shot, N=U) — f16 dot2
// ---------------------------------------------------------------------------
__global__ __launch_bounds__(256) void pgemm_kernel(
    const float* __restrict__ x,     // [B, T, D]
    const float* __restrict__ Wx,    // [D, U]
    const float* __restrict__ bias,  // [U]
    float* __restrict__ P)           // [T*B, U]  (== d_out)
{
    __shared__ u32 xs[128][66];      // [row][k-pair]   (+2 pad)
    __shared__ u32 ws[64][132];      // [k-pair][col]   (+4 pad)

    const int rb  = blockIdx.x;
    const int cb  = blockIdx.y;
    const int tid = threadIdx.x;
    const int tr  = tid >> 4;
    const int tcc = tid & 15;

    const float4* x4 = (const float4*)x;
#pragma unroll
    for (int l = 0; l < 16; ++l) {
        int idx = tid + l * 256;
        int r   = idx >> 5;
        int q   = idx & 31;
        int m   = rb * 128 + r;
        int b_  = m & 127;
        int t_  = m >> 7;
        float4 v = x4[((size_t)b_ * T + t_) * 32 + q];
        xs[r][2 * q]     = pk(v.x, v.y);
        xs[r][2 * q + 1] = pk(v.z, v.w);
    }
    const float4* W4 = (const float4*)Wx;
#pragma unroll
    for (int l = 0; l < 8; ++l) {
        int idx = tid + l * 256;
        int kp  = idx >> 5;
        int q   = idx & 31;
        float4 a = W4[(size_t)(2 * kp)     * 128 + cb * 32 + q];
        float4 c = W4[(size_t)(2 * kp + 1) * 128 + cb * 32 + q];
        uint4 w;
        w.x = pk(a.x, c.x); w.y = pk(a.y, c.y);
        w.z = pk(a.z, c.z); w.w = pk(a.w, c.w);
        *(uint4*)&ws[kp][4 * q] = w;
    }
    __syncthreads();

    float acc[8][8];
#pragma unroll
    for (int i = 0; i < 8; ++i)
#pragma unroll
        for (int j = 0; j < 8; ++j) acc[i][j] = 0.f;

#pragma unroll 2
    for (int kp = 0; kp < 64; ++kp) {
        u32 xv[8], wv[8];
#pragma unroll
        for (int i = 0; i < 8; ++i) xv[i] = xs[tr + 16 * i][kp];
#pragma unroll
        for (int j = 0; j < 8; ++j) wv[j] = ws[kp][tcc + 16 * j];
#pragma unroll
        for (int i = 0; i < 8; ++i)
#pragma unroll
            for (int j = 0; j < 8; ++j)
                acc[i][j] = fdot2(xv[i], wv[j], acc[i][j]);
    }

#pragma unroll
    for (int j = 0; j < 8; ++j) {
        int c    = cb * 128 + tcc + 16 * j;
        float bv = bias[c];
#pragma unroll
        for (int i = 0; i < 8; ++i) {
            int m = rb * 128 + tr + 16 * i;
            P[(size_t)m * U + c] = acc[i][j] + bv;
        }
    }
}

// ---------------------------------------------------------------------------
// Kernel 2: recurrence, one WG (512 thr) per batch row.
// ---------------------------------------------------------------------------
__global__ __launch_bounds__(512)
__attribute__((amdgpu_waves_per_eu(2, 2)))
void rnn_kernel(
    const float* __restrict__ Wh,    // [U, U] f32
    float* __restrict__ out)         // [T*B, U]; P on entry, h on exit
{
    __shared__ __align__(16) u32 WhL[32768];      // 128 KB: W pairs 12..15
    __shared__ __align__(16) u32 part[2][2112];   // 2 x 8 rows x 264 (packed)
    __shared__ __align__(16) u32 hbuf[2][256];    // h pairs, parity dbuf

    const int tid = threadIdx.x;
    const int tk  = tid >> 5;        // 0..15 pair-block
    const int tc  = tid & 31;        // 0..31 col base
    const int wv  = tid >> 6;        // 0..7 wave
    const int b   = blockIdx.x;

    // ---- init: W registers (pairs 16tk+q, q=0..11) ----
    u32x16 W0, W1, W2, W3, W4, W5, W6, W7, W8, W9, W10, W11;
#define LOADW(q)                                                          \
    {                                                                     \
        const float* r0 = Wh + (size_t)((tk * 16 + (q)) * 2) * U + tc;    \
        _Pragma("unroll")                                                 \
        for (int j = 0; j < 16; ++j)                                      \
            W##q[j] = pk(r0[32 * j], r0[U + 32 * j]);                     \
    }
    LOADW(0)  LOADW(1)  LOADW(2)  LOADW(3)
    LOADW(4)  LOADW(5)  LOADW(6)  LOADW(7)
    LOADW(8)  LOADW(9)  LOADW(10) LOADW(11)
#undef LOADW

    // ---- init: LDS pairs 12..15, lane-major uint4 (batch = pl2*4+jc) ----
#pragma unroll
    for (int pl2 = 0; pl2 < 4; ++pl2) {
        const float* r0 = Wh + (size_t)((tk * 16 + 12 + pl2) * 2) * U + tc;
#pragma unroll
        for (int jc = 0; jc < 4; ++jc) {
            uint4 w;
            w.x = pk(r0[32 * (4 * jc + 0)], r0[U + 32 * (4 * jc + 0)]);
            w.y = pk(r0[32 * (4 * jc + 1)], r0[U + 32 * (4 * jc + 1)]);
            w.z = pk(r0[32 * (4 * jc + 2)], r0[U + 32 * (4 * jc + 2)]);
            w.w = pk(r0[32 * (4 * jc + 3)], r0[U + 32 * (4 * jc + 3)]);
            *(uint4*)&WhL[((pl2 * 4 + jc) * 512 + tid) * 4] = w;
        }
    }

    if (tid < 256) hbuf[0][tid] = 0u;   // h_0 = 0 (parity 0)
    __syncthreads();

    const uint4* WL4 = (const uint4*)WhL;
    float* outb = out + (size_t)b * U;

    // prologue: W batches 0..7 in flight for t=0
    uint4 wa = WL4[0 * 512 + tid], wb = WL4[1 * 512 + tid];
    uint4 wc = WL4[2 * 512 + tid], wd = WL4[3 * 512 + tid];
    uint4 we = WL4[4 * 512 + tid], wf = WL4[5 * 512 + tid];
    uint4 wg = WL4[6 * 512 + tid], wh = WL4[7 * 512 + tid];

    // P prefetch for t=0
    float pv0 = 0.f, pv1 = 0.f;
    if (tid < 256) { pv0 = outb[tid]; pv1 = outb[tid + 256]; }

    for (int t = 0; t < T; ++t) {
        const int par = t & 1;

        // next-step P prefetch (1 full step of latency)
        int tn = (t + 1 < T) ? (t + 1) : t;
        const float* prown = outb + (size_t)tn * (B * U);
        float nv0 = 0.f, nv1 = 0.f;
        if (tid < 256) { nv0 = prown[tid]; nv1 = prown[tid + 256]; }

        // h fragments (broadcast: 2 distinct addrs per wave)
        const uint4* hb4 = (const uint4*)hbuf[par];
        uint4 hv0 = hb4[4 * tk + 0];
        uint4 hv1 = hb4[4 * tk + 1];
        uint4 hv2 = hb4[4 * tk + 2];
        uint4 hv3 = hb4[4 * tk + 3];

        float acc[16];
#pragma unroll
        for (int j = 0; j < 16; ++j) acc[j] = 0.f;

#define DOT16(hq, Wq)                                                     \
        {                                                                 \
            u32 hq_ = (hq);                                               \
            _Pragma("unroll")                                             \
            for (int j = 0; j < 16; ++j)                                  \
                acc[j] = fdot2(hq_, Wq[j], acc[j]);                       \
        }
#define CONSUME(hq, Aq, Bq, Cq, Dq)                                       \
        {                                                                 \
            u32 hq_ = (hq);                                               \
            acc[0]  = fdot2(hq_, Aq.x, acc[0]);                           \
            acc[1]  = fdot2(hq_, Aq.y, acc[1]);                           \
            acc[2]  = fdot2(hq_, Aq.z, acc[2]);                           \
            acc[3]  = fdot2(hq_, Aq.w, acc[3]);                           \
            acc[4]  = fdot2(hq_, Bq.x, acc[4]);                           \
            acc[5]  = fdot2(hq_, Bq.y, acc[5]);                           \
            acc[6]  = fdot2(hq_, Bq.z, acc[6]);                           \
            acc[7]  = fdot2(hq_, Bq.w, acc[7]);                           \
            acc[8]  = fdot2(hq_, Cq.x, acc[8]);                           \
            acc[9]  = fdot2(hq_, Cq.y, acc[9]);                           \
            acc[10] = fdot2(hq_, Cq.z, acc[10]);                          \
            acc[11] = fdot2(hq_, Cq.w, acc[11]);                          \
            acc[12] = fdot2(hq_, Dq.x, acc[12]);                          \
            acc[13] = fdot2(hq_, Dq.y, acc[13]);                          \
            acc[14] = fdot2(hq_, Dq.z, acc[14]);                          \
            acc[15] = fdot2(hq_, Dq.w, acc[15]);                          \
        }
        DOT16(hv0.x, W0) DOT16(hv0.y, W1) DOT16(hv0.z, W2) DOT16(hv0.w, W3)
        DOT16(hv1.x, W4) DOT16(hv1.y, W5) DOT16(hv1.z, W6) DOT16(hv1.w, W7)

        // pair 12 (batches 0..3), then refill with batches 8..11
        CONSUME(hv3.x, wa, wb, wc, wd)
        wa = WL4[ 8 * 512 + tid]; wb = WL4[ 9 * 512 + tid];
        wc = WL4[10 * 512 + tid]; wd = WL4[11 * 512 + tid];

        DOT16(hv2.x, W8) DOT16(hv2.y, W9) DOT16(hv2.z, W10) DOT16(hv2.w, W11)

        // pair 13 (batches 4..7), refill with batches 12..15
        CONSUME(hv3.y, we, wf, wg, wh)
        we = WL4[12 * 512 + tid]; wf = WL4[13 * 512 + tid];
        wg = WL4[14 * 512 + tid]; wh = WL4[15 * 512 + tid];

        // pair 14 (batches 8..11), refill with NEXT STEP batches 0..3
        CONSUME(hv3.z, wa, wb, wc, wd)
        wa = WL4[0 * 512 + tid]; wb = WL4[1 * 512 + tid];
        wc = WL4[2 * 512 + tid]; wd = WL4[3 * 512 + tid];

        // pair 15 (batches 12..15), refill with NEXT STEP batches 4..7
        CONSUME(hv3.w, we, wf, wg, wh)
        we = WL4[4 * 512 + tid]; wf = WL4[5 * 512 + tid];
        wg = WL4[6 * 512 + tid]; wh = WL4[7 * 512 + tid];
#undef CONSUME
#undef DOT16

        // wave pre-reduce: combine the 2 tk-groups in this wave
#pragma unroll
        for (int j = 0; j < 16; ++j) acc[j] += __shfl_xor(acc[j], 32);

        // lanes<32 write packed partials: row = wave, col pair (c, c+256)
        if (!(tid & 32)) {
#pragma unroll
            for (int j = 0; j < 8; ++j)
                part[par][wv * 264 + tc + 32 * j] = pk(acc[j], acc[j + 8]);
        }

        __syncthreads();   // B1: partials visible (next-W loads draining)

        if (tid < 256) {
            float a0[8], a1[8];
#pragma unroll
            for (int i = 0; i < 8; ++i) {
                U32H2 w; w.u = part[par][i * 264 + tid];
                a0[i] = (float)w.h.x;
                a1[i] = (float)w.h.y;
            }
            float s0 = pv0 + (((a0[0] + a0[1]) + (a0[2] + a0[3]))
                            + ((a0[4] + a0[5]) + (a0[6] + a0[7])));
            float s1 = pv1 + (((a1[0] + a1[1]) + (a1[2] + a1[3]))
                            + ((a1[4] + a1[5]) + (a1[6] + a1[7])));
            float h0 = fast_tanh(s0);
            float h1 = fast_tanh(s1);
            float* prow = outb + (size_t)t * (B * U);
            prow[tid]       = h0;          // final output (f32)
            prow[tid + 256] = h1;
            float o0 = __shfl_xor(h0, 1);
            float o1 = __shfl_xor(h1, 1);
            if (!(tid & 1)) {
                hbuf[par ^ 1][tid >> 1]         = pk(h0, o0);
                hbuf[par ^ 1][128 + (tid >> 1)] = pk(h1, o1);
            }
        }

        __syncthreads();   // B2: h visible for next step
        pv0 = nv0; pv1 = nv1;
    }
}

// ---------------------------------------------------------------------------
extern "C" void kernel_launch(void* const* d_in, const int* in_sizes, int n_in,
                              void* d_out, int out_size, void* d_ws, size_t ws_size,
                              hipStream_t stream)
{
    (void)d_ws; (void)ws_size; (void)in_sizes; (void)n_in; (void)out_size;
    const float* x    = (const float*)d_in[0];  // [B, T, D]
    const float* Wx   = (const float*)d_in[1];  // [D, U]
    const float* Wh   = (const float*)d_in[2];  // [U, U]
    const float* bias = (const float*)d_in[3];  // [U]
    float* out = (float*)d_out;                 // [T, B, U]

    pgemm_kernel<<<dim3((T * B) / 128, U / 128), 256, 0, stream>>>(x, Wx, bias, out);
    rnn_kernel<<<B, 512, 0, stream>>>(Wh, out);
}

// Round 9
// 1444.555 us; speedup vs baseline: 10.9906x; 1.1423x over previous
//
#include <hip/hip_runtime.h>
#include <stddef.h>
#include <stdint.h>

// Elman RNN: out[t,b,u] = h_t = tanh(x_t @ Wx + h_{t-1} @ Wh + bias)
// B=128, T=512, D=128, U=512. Output [T, B, U] float32.
//
// pgemm (f16 dot2): P = x@Wx + bias -> d_out. (~15 us, validated r5/r6)
// rnn: ONE WG per batch row, but 1024 threads (16 waves = 4/SIMD):
//   kg = tid>>6 (0..15, == wave) owns k-pairs [16kg,16kg+16)
//   cg = tid&63 owns cols cg + 64j, j=0..7
//   W-words/thread = 128: 96 in arch VGPRs (12 x u32x8 -> fits the 128-VGPR
//   cap at 4 waves/EU with ~zero AGPR moves, unlike r6's 192@2waves) +
//   32 in LDS (128 KB, the unavoidable regfile-deficit stream).
//   h-reads are whole-wave broadcasts (wave == kg). Partials [16][256]
//   packed-f16 u32, single buffer (barriers order reuse). Reduce on 256 thr.

constexpr int B = 128;
constexpr int T = 512;
constexpr int D = 128;
constexpr int U = 512;

typedef _Float16 f16;
typedef _Float16 f16x2 __attribute__((ext_vector_type(2)));
typedef __fp16   fp16x2 __attribute__((ext_vector_type(2)));
typedef unsigned int u32;
typedef u32 u32x8 __attribute__((ext_vector_type(8)));

union U32H2 { u32 u; f16x2 h; fp16x2 p; };

static __device__ __forceinline__ u32 pk(float a, float b) {
    U32H2 c; c.p = __builtin_amdgcn_cvt_pkrtz(a, b); return c.u;
}

#if __has_builtin(__builtin_amdgcn_fdot2)
static __device__ __forceinline__ float fdot2(u32 a, u32 b, float c) {
    U32H2 x, y; x.u = a; y.u = b;
    return __builtin_amdgcn_fdot2(x.h, y.h, c, false);
}
#else
static __device__ __forceinline__ float fdot2(u32 a, u32 b, float c) {
    U32H2 x, y; x.u = a; y.u = b;
    return c + (float)x.h.x * (float)y.h.x + (float)x.h.y * (float)y.h.y;
}
#endif

static __device__ __forceinline__ float fast_tanh(float x) {
    float e = __expf(2.0f * x);
    return 1.0f - 2.0f * __builtin_amdgcn_rcpf(e + 1.0f);
}

// ---------------------------------------------------------------------------
// Kernel 1: P = x @ Wx + bias  (M=T*B, K=D=128 one-shot, N=U) — f16 dot2
// ---------------------------------------------------------------------------
__global__ __launch_bounds__(256) void pgemm_kernel(
    const float* __restrict__ x,     // [B, T, D]
    const float* __restrict__ Wx,    // [D, U]
    const float* __restrict__ bias,  // [U]
    float* __restrict__ P)           // [T*B, U]  (== d_out)
{
    __shared__ u32 xs[128][66];      // [row][k-pair]   (+2 pad)
    __shared__ u32 ws[64][132];      // [k-pair][col]   (+4 pad)

    const int rb  = blockIdx.x;
    const int cb  = blockIdx.y;
    const int tid = threadIdx.x;
    const int tr  = tid >> 4;
    const int tcc = tid & 15;

    const float4* x4 = (const float4*)x;
#pragma unroll
    for (int l = 0; l < 16; ++l) {
        int idx = tid + l * 256;
        int r   = idx >> 5;
        int q   = idx & 31;
        int m   = rb * 128 + r;
        int b_  = m & 127;
        int t_  = m >> 7;
        float4 v = x4[((size_t)b_ * T + t_) * 32 + q];
        xs[r][2 * q]     = pk(v.x, v.y);
        xs[r][2 * q + 1] = pk(v.z, v.w);
    }
    const float4* W4 = (const float4*)Wx;
#pragma unroll
    for (int l = 0; l < 8; ++l) {
        int idx = tid + l * 256;
        int kp  = idx >> 5;
        int q   = idx & 31;
        float4 a = W4[(size_t)(2 * kp)     * 128 + cb * 32 + q];
        float4 c = W4[(size_t)(2 * kp + 1) * 128 + cb * 32 + q];
        uint4 w;
        w.x = pk(a.x, c.x); w.y = pk(a.y, c.y);
        w.z = pk(a.z, c.z); w.w = pk(a.w, c.w);
        *(uint4*)&ws[kp][4 * q] = w;
    }
    __syncthreads();

    float acc[8][8];
#pragma unroll
    for (int i = 0; i < 8; ++i)
#pragma unroll
        for (int j = 0; j < 8; ++j) acc[i][j] = 0.f;

#pragma unroll 2
    for (int kp = 0; kp < 64; ++kp) {
        u32 xv[8], wv[8];
#pragma unroll
        for (int i = 0; i < 8; ++i) xv[i] = xs[tr + 16 * i][kp];
#pragma unroll
        for (int j = 0; j < 8; ++j) wv[j] = ws[kp][tcc + 16 * j];
#pragma unroll
        for (int i = 0; i < 8; ++i)
#pragma unroll
            for (int j = 0; j < 8; ++j)
                acc[i][j] = fdot2(xv[i], wv[j], acc[i][j]);
    }

#pragma unroll
    for (int j = 0; j < 8; ++j) {
        int c    = cb * 128 + tcc + 16 * j;
        float bv = bias[c];
#pragma unroll
        for (int i = 0; i < 8; ++i) {
            int m = rb * 128 + tr + 16 * i;
            P[(size_t)m * U + c] = acc[i][j] + bv;
        }
    }
}

// ---------------------------------------------------------------------------
// Kernel 2: recurrence, one WG (1024 thr, 16 waves) per batch row.
// ---------------------------------------------------------------------------
__global__ __launch_bounds__(1024)
__attribute__((amdgpu_waves_per_eu(4, 4)))
void rnn_kernel(
    const float* __restrict__ Wh,    // [U, U] f32
    float* __restrict__ out)         // [T*B, U]; P on entry, h on exit
{
    __shared__ __align__(16) u32 WhL[32768];   // 128 KB: W pairs q=12..15
    __shared__ __align__(16) u32 part[4096];   // 16 KB [16 kg][256 pk-cols]
    __shared__ __align__(16) u32 hbuf[256];    // 1 KB: h pair p -> u32 p

    const int tid = threadIdx.x;
    const int kg  = tid >> 6;        // 0..15  (== wave index)
    const int cg  = tid & 63;        // 0..63  col base (cols cg + 64j)
    const int b   = blockIdx.x;

    // ---- init: W regs q=0..11 (rows 2(16kg+q), 2(16kg+q)+1, col cg+64j) ----
    u32x8 W0, W1, W2, W3, W4, W5, W6, W7, W8, W9, W10, W11;
#define LOADW(q)                                                          \
    {                                                                     \
        const float* r0 = Wh + (size_t)(32 * kg + 2 * (q)) * U + cg;      \
        _Pragma("unroll")                                                 \
        for (int j = 0; j < 8; ++j)                                       \
            W##q[j] = pk(r0[64 * j], r0[U + 64 * j]);                     \
    }
    LOADW(0)  LOADW(1)  LOADW(2)  LOADW(3)
    LOADW(4)  LOADW(5)  LOADW(6)  LOADW(7)
    LOADW(8)  LOADW(9)  LOADW(10) LOADW(11)
#undef LOADW

    // ---- init: W LDS q=12..15, uint4 slot idx = (q-12)*2 + (j>>2) ----
#pragma unroll
    for (int qq = 0; qq < 4; ++qq) {
        const float* r0 = Wh + (size_t)(32 * kg + 24 + 2 * qq) * U + cg;
#pragma unroll
        for (int i = 0; i < 2; ++i) {
            uint4 w;
            w.x = pk(r0[64 * (4 * i + 0)], r0[U + 64 * (4 * i + 0)]);
            w.y = pk(r0[64 * (4 * i + 1)], r0[U + 64 * (4 * i + 1)]);
            w.z = pk(r0[64 * (4 * i + 2)], r0[U + 64 * (4 * i + 2)]);
            w.w = pk(r0[64 * (4 * i + 3)], r0[U + 64 * (4 * i + 3)]);
            *(uint4*)&WhL[(size_t)(qq * 2 + i) * 4096 + tid * 4] = w;
        }
    }

    if (tid < 256) hbuf[tid] = 0u;   // h_0 = 0
    __syncthreads();

    const uint4* WL4 = (const uint4*)WhL;
    float* outb = out + (size_t)b * U;

    // P prefetch for t=0 (threads 0..255 own output cols tid, tid+256)
    float pv0 = 0.f, pv1 = 0.f;
    if (tid < 256) { pv0 = outb[tid]; pv1 = outb[tid + 256]; }

    for (int t = 0; t < T; ++t) {
        // next-step P prefetch (one full step of latency to hide)
        int tn = (t + 1 < T) ? (t + 1) : t;
        const float* prown = outb + (size_t)tn * (B * U);
        float nv0 = 0.f, nv1 = 0.f;
        if (tid < 256) { nv0 = prown[tid]; nv1 = prown[tid + 256]; }

        // h fragments: whole-wave broadcast (kg == wave)
        const uint4* hb4 = (const uint4*)hbuf;
        uint4 h0 = hb4[4 * kg + 0];
        uint4 h1 = hb4[4 * kg + 1];
        uint4 h2 = hb4[4 * kg + 2];
        uint4 h3 = hb4[4 * kg + 3];

        // stage LDS-W q12, q13 (2 uint4 each)
        uint4 wlA = WL4[0 * 1024 + tid], wlB = WL4[1 * 1024 + tid];
        uint4 wlC = WL4[2 * 1024 + tid], wlD = WL4[3 * 1024 + tid];

        float acc[8];
#pragma unroll
        for (int j = 0; j < 8; ++j) acc[j] = 0.f;

#define DOT8(hq, Wq)                                                      \
        {                                                                 \
            u32 hq_ = (hq);                                               \
            _Pragma("unroll")                                             \
            for (int j = 0; j < 8; ++j)                                   \
                acc[j] = fdot2(hq_, Wq[j], acc[j]);                       \
        }
#define CONSUME8(hq, Aq, Bq)                                              \
        {                                                                 \
            u32 hq_ = (hq);                                               \
            acc[0] = fdot2(hq_, Aq.x, acc[0]);                            \
            acc[1] = fdot2(hq_, Aq.y, acc[1]);                            \
            acc[2] = fdot2(hq_, Aq.z, acc[2]);                            \
            acc[3] = fdot2(hq_, Aq.w, acc[3]);                            \
            acc[4] = fdot2(hq_, Bq.x, acc[4]);                            \
            acc[5] = fdot2(hq_, Bq.y, acc[5]);                            \
            acc[6] = fdot2(hq_, Bq.z, acc[6]);                            \
            acc[7] = fdot2(hq_, Bq.w, acc[7]);                            \
        }
        DOT8(h0.x, W0) DOT8(h0.y, W1) DOT8(h0.z, W2) DOT8(h0.w, W3)
        DOT8(h1.x, W4) DOT8(h1.y, W5)

        CONSUME8(h3.x, wlA, wlB)                    // q12
        wlA = WL4[4 * 1024 + tid]; wlB = WL4[5 * 1024 + tid];   // q14

        DOT8(h1.z, W6) DOT8(h1.w, W7) DOT8(h2.x, W8) DOT8(h2.y, W9)

        CONSUME8(h3.y, wlC, wlD)                    // q13
        wlC = WL4[6 * 1024 + tid]; wlD = WL4[7 * 1024 + tid];   // q15

        DOT8(h2.z, W10) DOT8(h2.w, W11)

        CONSUME8(h3.z, wlA, wlB)                    // q14
        CONSUME8(h3.w, wlC, wlD)                    // q15
#undef CONSUME8
#undef DOT8

        // packed partials: col pair (cg+64j, cg+64j+256), j=0..3
#pragma unroll
        for (int j = 0; j < 4; ++j)
            part[kg * 256 + cg + 64 * j] = pk(acc[j], acc[j + 4]);

        __syncthreads();   // B1: partials visible

        if (tid < 256) {
            float a0[16], a1[16];
#pragma unroll
            for (int i = 0; i < 16; ++i) {
                U32H2 w; w.u = part[i * 256 + tid];
                a0[i] = (float)w.h.x;
                a1[i] = (float)w.h.y;
            }
            float s0 = pv0, s1 = pv1;
#pragma unroll
            for (int d = 1; d < 16; d <<= 1)
#pragma unroll
                for (int i = 0; i < 16; i += 2 * d) {
                    a0[i] += a0[i + d];
                    a1[i] += a1[i + d];
                }
            s0 += a0[0];
            s1 += a1[0];
            float h0v = fast_tanh(s0);
            float h1v = fast_tanh(s1);
            float* prow = outb + (size_t)t * (B * U);
            prow[tid]       = h0v;          // final output (f32)
            prow[tid + 256] = h1v;
            float o0 = __shfl_xor(h0v, 1);
            float o1 = __shfl_xor(h1v, 1);
            if (!(tid & 1)) {
                hbuf[tid >> 1]         = pk(h0v, o0);
                hbuf[128 + (tid >> 1)] = pk(h1v, o1);
            }
        }

        __syncthreads();   // B2: h visible for next step
        pv0 = nv0; pv1 = nv1;
    }
}

// ---------------------------------------------------------------------------
extern "C" void kernel_launch(void* const* d_in, const int* in_sizes, int n_in,
                              void* d_out, int out_size, void* d_ws, size_t ws_size,
                              hipStream_t stream)
{
    (void)d_ws; (void)ws_size; (void)in_sizes; (void)n_in; (void)out_size;
    const float* x    = (const float*)d_in[0];  // [B, T, D]
    const float* Wx   = (const float*)d_in[1];  // [D, U]
    const float* Wh   = (const float*)d_in[2];  // [U, U]
    const float* bias = (const float*)d_in[3];  // [U]
    float* out = (float*)d_out;                 // [T, B, U]

    pgemm_kernel<<<dim3((T * B) / 128, U / 128), 256, 0, stream>>>(x, Wx, bias, out);
    rnn_kernel<<<B, 1024, 0, stream>>>(Wh, out);
}

// Round 10
// 997.616 us; speedup vs baseline: 15.9145x; 1.4480x over previous
//
#include <hip/hip_runtime.h>
#include <stddef.h>
#include <stdint.h>

// Elman RNN: out[t,b,u] = h_t = tanh(x_t @ Wx + h_{t-1} @ Wh + bias)
// B=128, T=512, D=128, U=512. Output [T, B, U] float32.
//
// pgemm (f16 dot2): P = x@Wx + bias -> d_out. (~15 us, validated)
// rnn (MFMA pivot): one WG (512 thr, 8 waves) per batch row.
//   Wave w owns cols [64w, 64w+64) = 4 col-tiles of 16.
//   Per step: 64 x mfma_f32_16x16x32_f16 (4 tiles x 16 k-slabs), M=1 (rows
//   1..15 zero). W held as B-fragments: 48 frags in registers (VGPR OR AGPR —
//   MFMA reads AGPR natively, ending the 5-round accvgpr-move tax) +
//   16 frags in LDS (128 KB, the regfile-deficit stream, ~1540 cy/step).
//   A-frags: only lanes l%16==0 carry h (masked 16B loads) -> ~1KB/wave/step.
//   No partials, no reduce, ONE barrier/step (h parity dbuf).
//   Layouts (AMD matrix calc, consistent with m89-verified C/D):
//     A[i][k]:  lane = i + 16*(k/8), elem e = k%8
//     B[k][j]:  lane = j + 16*(k/8), elem e = k%8
//     D[i][j]:  lane = j + 16*(i/4), reg  r = i%4   (row 0 -> lanes 0-15, .x)

constexpr int B = 128;
constexpr int T = 512;
constexpr int D = 128;
constexpr int U = 512;

typedef _Float16 f16;
typedef _Float16 f16x2 __attribute__((ext_vector_type(2)));
typedef _Float16 f16x8 __attribute__((ext_vector_type(8)));
typedef __fp16   fp16x2 __attribute__((ext_vector_type(2)));
typedef float    f32x4 __attribute__((ext_vector_type(4)));
typedef unsigned int u32;

union U32H2 { u32 u; f16x2 h; fp16x2 p; };

static __device__ __forceinline__ u32 pk(float a, float b) {
    U32H2 c; c.p = __builtin_amdgcn_cvt_pkrtz(a, b); return c.u;
}

#if __has_builtin(__builtin_amdgcn_fdot2)
static __device__ __forceinline__ float fdot2(u32 a, u32 b, float c) {
    U32H2 x, y; x.u = a; y.u = b;
    return __builtin_amdgcn_fdot2(x.h, y.h, c, false);
}
#else
static __device__ __forceinline__ float fdot2(u32 a, u32 b, float c) {
    U32H2 x, y; x.u = a; y.u = b;
    return c + (float)x.h.x * (float)y.h.x + (float)x.h.y * (float)y.h.y;
}
#endif

static __device__ __forceinline__ float fast_tanh(float x) {
    float e = __expf(2.0f * x);
    return 1.0f - 2.0f * __builtin_amdgcn_rcpf(e + 1.0f);
}

// ---------------------------------------------------------------------------
// Kernel 1: P = x @ Wx + bias  (M=T*B, K=D=128 one-shot, N=U) — f16 dot2
// ---------------------------------------------------------------------------
__global__ __launch_bounds__(256) void pgemm_kernel(
    const float* __restrict__ x,     // [B, T, D]
    const float* __restrict__ Wx,    // [D, U]
    const float* __restrict__ bias,  // [U]
    float* __restrict__ P)           // [T*B, U]  (== d_out)
{
    __shared__ u32 xs[128][66];      // [row][k-pair]   (+2 pad)
    __shared__ u32 ws[64][132];      // [k-pair][col]   (+4 pad)

    const int rb  = blockIdx.x;
    const int cb  = blockIdx.y;
    const int tid = threadIdx.x;
    const int tr  = tid >> 4;
    const int tcc = tid & 15;

    const float4* x4 = (const float4*)x;
#pragma unroll
    for (int l = 0; l < 16; ++l) {
        int idx = tid + l * 256;
        int r   = idx >> 5;
        int q   = idx & 31;
        int m   = rb * 128 + r;
        int b_  = m & 127;
        int t_  = m >> 7;
        float4 v = x4[((size_t)b_ * T + t_) * 32 + q];
        xs[r][2 * q]     = pk(v.x, v.y);
        xs[r][2 * q + 1] = pk(v.z, v.w);
    }
    const float4* W4 = (const float4*)Wx;
#pragma unroll
    for (int l = 0; l < 8; ++l) {
        int idx = tid + l * 256;
        int kp  = idx >> 5;
        int q   = idx & 31;
        float4 a = W4[(size_t)(2 * kp)     * 128 + cb * 32 + q];
        float4 c = W4[(size_t)(2 * kp + 1) * 128 + cb * 32 + q];
        uint4 w;
        w.x = pk(a.x, c.x); w.y = pk(a.y, c.y);
        w.z = pk(a.z, c.z); w.w = pk(a.w, c.w);
        *(uint4*)&ws[kp][4 * q] = w;
    }
    __syncthreads();

    float acc[8][8];
#pragma unroll
    for (int i = 0; i < 8; ++i)
#pragma unroll
        for (int j = 0; j < 8; ++j) acc[i][j] = 0.f;

#pragma unroll 2
    for (int kp = 0; kp < 64; ++kp) {
        u32 xv[8], wv[8];
#pragma unroll
        for (int i = 0; i < 8; ++i) xv[i] = xs[tr + 16 * i][kp];
#pragma unroll
        for (int j = 0; j < 8; ++j) wv[j] = ws[kp][tcc + 16 * j];
#pragma unroll
        for (int i = 0; i < 8; ++i)
#pragma unroll
            for (int j = 0; j < 8; ++j)
                acc[i][j] = fdot2(xv[i], wv[j], acc[i][j]);
    }

#pragma unroll
    for (int j = 0; j < 8; ++j) {
        int c    = cb * 128 + tcc + 16 * j;
        float bv = bias[c];
#pragma unroll
        for (int i = 0; i < 8; ++i) {
            int m = rb * 128 + tr + 16 * i;
            P[(size_t)m * U + c] = acc[i][j] + bv;
        }
    }
}

// ---------------------------------------------------------------------------
// Kernel 2: recurrence via MFMA, one WG (512 thr, 8 waves) per batch row.
// ---------------------------------------------------------------------------
__global__ __launch_bounds__(512, 2) void rnn_kernel(
    const float* __restrict__ Wh,    // [U, U] f32
    float* __restrict__ out)         // [T*B, U]; P on entry, h on exit
{
    __shared__ __align__(16) u32 WL[32768];      // 128 KB: W frags s=12..15
    __shared__ __align__(16) u32 hbuf[2][256];   // h f16 [2 parity][512]

    const int tid = threadIdx.x;
    const int w   = tid >> 6;        // wave 0..7 (owns cols 64w..64w+63)
    const int l   = tid & 63;        // lane
    const int lg  = l >> 4;          // k-octet group 0..3
    const int lc  = l & 15;          // col-in-tile / row-in-A
    const int b   = blockIdx.x;

    // ---- init: B-fragments of Wh (f32 -> f16) ----
    // frag(ct, s) elem e = Wh[32s + 8*lg + e][64w + 16ct + lc]
    f16x8 Wf[4][12];                 // slabs 0..11 in registers (VGPR/AGPR)
#pragma unroll
    for (int ct = 0; ct < 4; ++ct) {
#pragma unroll
        for (int s = 0; s < 12; ++s) {
            const float* src = Wh + (size_t)(32 * s + 8 * lg) * U
                             + 64 * w + 16 * ct + lc;
            f16x8 f;
#pragma unroll
            for (int e = 0; e < 8; ++e) f[e] = (f16)src[(size_t)e * U];
            Wf[ct][s] = f;
        }
    }
    // slabs 12..15 -> LDS, slot = (w*16 + sr*4 + ct), 16 B per lane
#pragma unroll
    for (int sr = 0; sr < 4; ++sr) {
#pragma unroll
        for (int ct = 0; ct < 4; ++ct) {
            const float* src = Wh + (size_t)(32 * (12 + sr) + 8 * lg) * U
                             + 64 * w + 16 * ct + lc;
            f16x8 f;
#pragma unroll
            for (int e = 0; e < 8; ++e) f[e] = (f16)src[(size_t)e * U];
            *(f16x8*)&WL[((w * 16 + sr * 4 + ct) * 64 + l) * 4] = f;
        }
    }

    if (tid < 256) { hbuf[0][tid] = 0u; hbuf[1][tid] = 0u; }
    __syncthreads();

    float* outb = out + (size_t)b * U;

    // P prefetch for t=0 (lanes 0-15 of each wave own cols 64w+16ct+lc)
    float pv0 = 0.f, pv1 = 0.f, pv2 = 0.f, pv3 = 0.f;
    if (l < 16) {
        pv0 = outb[64 * w + 0  + lc];
        pv1 = outb[64 * w + 16 + lc];
        pv2 = outb[64 * w + 32 + lc];
        pv3 = outb[64 * w + 48 + lc];
    }

    for (int t = 0; t < T; ++t) {
        const int par = t & 1;
        const f16* hb = (const f16*)hbuf[par];

        f32x4 acc0 = (f32x4)0.f, acc1 = (f32x4)0.f;
        f32x4 acc2 = (f32x4)0.f, acc3 = (f32x4)0.f;

        // A-frag: only lanes lc==0 carry data: h[32s + 8*lg + e]
#define ALOAD(s)                                                          \
        ({                                                                \
            f16x8 a_ = (f16x8)0;                                          \
            if (lc == 0)                                                  \
                a_ = *(const f16x8*)&hb[32 * (s) + 8 * lg];               \
            a_;                                                           \
        })

        // slabs 0..11 from registers
#pragma unroll
        for (int s = 0; s < 12; ++s) {
            f16x8 a = ALOAD(s);
            acc0 = __builtin_amdgcn_mfma_f32_16x16x32_f16(a, Wf[0][s], acc0, 0, 0, 0);
            acc1 = __builtin_amdgcn_mfma_f32_16x16x32_f16(a, Wf[1][s], acc1, 0, 0, 0);
            acc2 = __builtin_amdgcn_mfma_f32_16x16x32_f16(a, Wf[2][s], acc2, 0, 0, 0);
            acc3 = __builtin_amdgcn_mfma_f32_16x16x32_f16(a, Wf[3][s], acc3, 0, 0, 0);
        }
        // slabs 12..15 from LDS (the capacity-deficit stream)
#pragma unroll
        for (int sr = 0; sr < 4; ++sr) {
            f16x8 a = ALOAD(12 + sr);
            f16x8 b0 = *(const f16x8*)&WL[((w * 16 + sr * 4 + 0) * 64 + l) * 4];
            f16x8 b1 = *(const f16x8*)&WL[((w * 16 + sr * 4 + 1) * 64 + l) * 4];
            f16x8 b2 = *(const f16x8*)&WL[((w * 16 + sr * 4 + 2) * 64 + l) * 4];
            f16x8 b3 = *(const f16x8*)&WL[((w * 16 + sr * 4 + 3) * 64 + l) * 4];
            acc0 = __builtin_amdgcn_mfma_f32_16x16x32_f16(a, b0, acc0, 0, 0, 0);
            acc1 = __builtin_amdgcn_mfma_f32_16x16x32_f16(a, b1, acc1, 0, 0, 0);
            acc2 = __builtin_amdgcn_mfma_f32_16x16x32_f16(a, b2, acc2, 0, 0, 0);
            acc3 = __builtin_amdgcn_mfma_f32_16x16x32_f16(a, b3, acc3, 0, 0, 0);
        }
#undef ALOAD

        // tail: row 0 of D lives in lanes 0-15, reg .x
        float nv0 = 0.f, nv1 = 0.f, nv2 = 0.f, nv3 = 0.f;
        if (l < 16) {
            float* prow = outb + (size_t)t * (B * U);
            const float* prown = outb + (size_t)((t + 1 < T) ? t + 1 : t) * (B * U);
            f16* hbn = (f16*)hbuf[par ^ 1];

            float h0 = fast_tanh(pv0 + acc0.x);
            float h1 = fast_tanh(pv1 + acc1.x);
            float h2 = fast_tanh(pv2 + acc2.x);
            float h3 = fast_tanh(pv3 + acc3.x);
            prow[64 * w + 0  + lc] = h0;
            prow[64 * w + 16 + lc] = h1;
            prow[64 * w + 32 + lc] = h2;
            prow[64 * w + 48 + lc] = h3;
            hbn[64 * w + 0  + lc] = (f16)h0;
            hbn[64 * w + 16 + lc] = (f16)h1;
            hbn[64 * w + 32 + lc] = (f16)h2;
            hbn[64 * w + 48 + lc] = (f16)h3;

            nv0 = prown[64 * w + 0  + lc];
            nv1 = prown[64 * w + 16 + lc];
            nv2 = prown[64 * w + 32 + lc];
            nv3 = prown[64 * w + 48 + lc];
        }

        __syncthreads();   // h(par^1) visible for next step
        pv0 = nv0; pv1 = nv1; pv2 = nv2; pv3 = nv3;
    }
}

// ---------------------------------------------------------------------------
extern "C" void kernel_launch(void* const* d_in, const int* in_sizes, int n_in,
                              void* d_out, int out_size, void* d_ws, size_t ws_size,
                              hipStream_t stream)
{
    (void)d_ws; (void)ws_size; (void)in_sizes; (void)n_in; (void)out_size;
    const float* x    = (const float*)d_in[0];  // [B, T, D]
    const float* Wx   = (const float*)d_in[1];  // [D, U]
    const float* Wh   = (const float*)d_in[2];  // [U, U]
    const float* bias = (const float*)d_in[3];  // [U]
    float* out = (float*)d_out;                 // [T, B, U]

    pgemm_kernel<<<dim3((T * B) / 128, U / 128), 256, 0, stream>>>(x, Wx, bias, out);
    rnn_kernel<<<B, 512, 0, stream>>>(Wh, out);
}

// Round 13
// 836.537 us; speedup vs baseline: 18.9789x; 1.1926x over previous
//
#include <hip/hip_runtime.h>
#include <stddef.h>
#include <stdint.h>

// Elman RNN: out[t,b,u] = h_t = tanh(x_t @ Wx + h_{t-1} @ Wh + bias)
// B=128, T=512, D=128, U=512. Output [T, B, U] float32.
//
// pgemm (f16 dot2): P = x@Wx + bias -> d_out. (~15 us, validated)
// rnn (builtin MFMA, round-10 structure): one WG (512 thr, 8 waves) per row.
//   Wave w owns cols [64w, 64w+64) = 4 col-tiles. 64 MFMAs/wave/step.
//   W as B-fragments: 48 frags/thread REGISTER-RESIDENT, 16 frags in LDS.
//   Round-13 changes vs round 10 (passed, 981 us):
//    * Wf frags pinned via asm("" : "+v") after init — kills the allocator's
//      remat-from-global choice (r10 tell: FETCH 92.5MB >> 33MB inputs, i.e.
//      W was re-loaded through L2 every step = the latency wall).
//    * A-loads broadcast, unmasked (only D row 0 is consumed; saves the
//      per-load cndmask chains).
//    * LDS-slab reads interleaved between register-slab MFMA groups.
//   Unified budget: 192 Wf + 16 acc + 16 stage + 4 A + 8 pv + ~15 misc ~ 251
//   <= 256/wave (pool 2048/CU at 8 waves).
//   Layouts (validated r10, absmax 0.0039):
//     A[i][k]: lane = i + 16*(k/8), elem = k%8   (row 0 broadcast to all i)
//     B[k][j]: lane = j + 16*(k/8), elem = k%8
//     D[i][j]: lane = j + 16*(i/4), reg = i%4    (row 0 -> lanes 0-15, .x)

constexpr int B = 128;
constexpr int T = 512;
constexpr int D = 128;
constexpr int U = 512;

typedef _Float16 f16;
typedef _Float16 f16x2 __attribute__((ext_vector_type(2)));
typedef _Float16 f16x8 __attribute__((ext_vector_type(8)));
typedef __fp16   fp16x2 __attribute__((ext_vector_type(2)));
typedef float    f32x4 __attribute__((ext_vector_type(4)));
typedef unsigned int u32;

union U32H2 { u32 u; f16x2 h; fp16x2 p; };

static __device__ __forceinline__ u32 pk(float a, float b) {
    U32H2 c; c.p = __builtin_amdgcn_cvt_pkrtz(a, b); return c.u;
}

#if __has_builtin(__builtin_amdgcn_fdot2)
static __device__ __forceinline__ float fdot2(u32 a, u32 b, float c) {
    U32H2 x, y; x.u = a; y.u = b;
    return __builtin_amdgcn_fdot2(x.h, y.h, c, false);
}
#else
static __device__ __forceinline__ float fdot2(u32 a, u32 b, float c) {
    U32H2 x, y; x.u = a; y.u = b;
    return c + (float)x.h.x * (float)y.h.x + (float)x.h.y * (float)y.h.y;
}
#endif

static __device__ __forceinline__ float fast_tanh(float x) {
    float e = __expf(2.0f * x);
    return 1.0f - 2.0f * __builtin_amdgcn_rcpf(e + 1.0f);
}

// ---------------------------------------------------------------------------
// Kernel 1: P = x @ Wx + bias  (M=T*B, K=D=128 one-shot, N=U) — f16 dot2
// ---------------------------------------------------------------------------
__global__ __launch_bounds__(256) void pgemm_kernel(
    const float* __restrict__ x,     // [B, T, D]
    const float* __restrict__ Wx,    // [D, U]
    const float* __restrict__ bias,  // [U]
    float* __restrict__ P)           // [T*B, U]  (== d_out)
{
    __shared__ u32 xs[128][66];      // [row][k-pair]   (+2 pad)
    __shared__ u32 ws[64][132];      // [k-pair][col]   (+4 pad)

    const int rb  = blockIdx.x;
    const int cb  = blockIdx.y;
    const int tid = threadIdx.x;
    const int tr  = tid >> 4;
    const int tcc = tid & 15;

    const float4* x4 = (const float4*)x;
#pragma unroll
    for (int l = 0; l < 16; ++l) {
        int idx = tid + l * 256;
        int r   = idx >> 5;
        int q   = idx & 31;
        int m   = rb * 128 + r;
        int b_  = m & 127;
        int t_  = m >> 7;
        float4 v = x4[((size_t)b_ * T + t_) * 32 + q];
        xs[r][2 * q]     = pk(v.x, v.y);
        xs[r][2 * q + 1] = pk(v.z, v.w);
    }
    const float4* W4 = (const float4*)Wx;
#pragma unroll
    for (int l = 0; l < 8; ++l) {
        int idx = tid + l * 256;
        int kp  = idx >> 5;
        int q   = idx & 31;
        float4 a = W4[(size_t)(2 * kp)     * 128 + cb * 32 + q];
        float4 c = W4[(size_t)(2 * kp + 1) * 128 + cb * 32 + q];
        uint4 w;
        w.x = pk(a.x, c.x); w.y = pk(a.y, c.y);
        w.z = pk(a.z, c.z); w.w = pk(a.w, c.w);
        *(uint4*)&ws[kp][4 * q] = w;
    }
    __syncthreads();

    float acc[8][8];
#pragma unroll
    for (int i = 0; i < 8; ++i)
#pragma unroll
        for (int j = 0; j < 8; ++j) acc[i][j] = 0.f;

#pragma unroll 2
    for (int kp = 0; kp < 64; ++kp) {
        u32 xv[8], wv[8];
#pragma unroll
        for (int i = 0; i < 8; ++i) xv[i] = xs[tr + 16 * i][kp];
#pragma unroll
        for (int j = 0; j < 8; ++j) wv[j] = ws[kp][tcc + 16 * j];
#pragma unroll
        for (int i = 0; i < 8; ++i)
#pragma unroll
            for (int j = 0; j < 8; ++j)
                acc[i][j] = fdot2(xv[i], wv[j], acc[i][j]);
    }

#pragma unroll
    for (int j = 0; j < 8; ++j) {
        int c    = cb * 128 + tcc + 16 * j;
        float bv = bias[c];
#pragma unroll
        for (int i = 0; i < 8; ++i) {
            int m = rb * 128 + tr + 16 * i;
            P[(size_t)m * U + c] = acc[i][j] + bv;
        }
    }
}

// ---------------------------------------------------------------------------
// Kernel 2: recurrence via MFMA, one WG (512 thr) per batch row.
// ---------------------------------------------------------------------------
__global__ __launch_bounds__(512, 2) void rnn_kernel(
    const float* __restrict__ Wh,    // [U, U] f32
    float* __restrict__ out)         // [T*B, U]; P on entry, h on exit
{
    __shared__ __align__(16) u32 WL[32768];      // 128 KB: W frags s=12..15
    __shared__ __align__(16) u32 hbuf[2][256];   // h f16 [2 parity][512]

    const int tid = threadIdx.x;
    const int w   = tid >> 6;        // wave 0..7 (owns cols 64w..64w+63)
    const int l   = tid & 63;        // lane
    const int lg  = l >> 4;          // k-octet group 0..3
    const int lc  = l & 15;          // col-in-tile
    const int b   = blockIdx.x;

    // ---- init: B-fragments of Wh (f32 -> f16) ----
    // frag(ct, s) elem e = Wh[32s + 8*lg + e][64w + 16ct + lc]
    f16x8 Wf[4][12];                 // slabs 0..11 -> register-resident
#pragma unroll
    for (int ct = 0; ct < 4; ++ct) {
#pragma unroll
        for (int s = 0; s < 12; ++s) {
            const float* src = Wh + (size_t)(32 * s + 8 * lg) * U
                             + 64 * w + 16 * ct + lc;
            f16x8 f;
#pragma unroll
            for (int e = 0; e < 8; ++e) f[e] = (f16)src[(size_t)e * U];
            Wf[ct][s] = f;
        }
    }
    // PIN: opaque def -> compiler cannot rematerialize Wf from global inside
    // the t-loop (round 10's hidden cost: FETCH 92.5MB = per-step W reloads).
#pragma unroll
    for (int ct = 0; ct < 4; ++ct)
#pragma unroll
        for (int s = 0; s < 12; ++s)
            asm("" : "+v"(Wf[ct][s]));

    // slabs 12..15 -> LDS, slot = (w*16 + sr*4 + ct), 16 B per lane
#pragma unroll
    for (int sr = 0; sr < 4; ++sr) {
#pragma unroll
        for (int ct = 0; ct < 4; ++ct) {
            const float* src = Wh + (size_t)(32 * (12 + sr) + 8 * lg) * U
                             + 64 * w + 16 * ct + lc;
            f16x8 f;
#pragma unroll
            for (int e = 0; e < 8; ++e) f[e] = (f16)src[(size_t)e * U];
            *(f16x8*)&WL[((w * 16 + sr * 4 + ct) * 64 + l) * 4] = f;
        }
    }

    if (tid < 256) { hbuf[0][tid] = 0u; hbuf[1][tid] = 0u; }
    __syncthreads();

    float* outb = out + (size_t)b * U;

    // P prefetch for t=0 (lanes 0-15 of each wave own cols 64w+16ct+lc)
    float pv0 = 0.f, pv1 = 0.f, pv2 = 0.f, pv3 = 0.f;
    if (l < 16) {
        pv0 = outb[64 * w + 0  + lc];
        pv1 = outb[64 * w + 16 + lc];
        pv2 = outb[64 * w + 32 + lc];
        pv3 = outb[64 * w + 48 + lc];
    }

    for (int t = 0; t < T; ++t) {
        const int par = t & 1;
        const f16* hb = (const f16*)hbuf[par];

        f32x4 acc0 = (f32x4)0.f, acc1 = (f32x4)0.f;
        f32x4 acc2 = (f32x4)0.f, acc3 = (f32x4)0.f;

        // A-frag: whole-wave broadcast of h octet (rows 1..15 of A are
        // harmless copies; only D row 0 is consumed).
#define ALOAD(s) (*(const f16x8*)&hb[32 * (s) + 8 * lg])
#define WLREAD(fi) (*(const f16x8*)&WL[((w * 16 + (fi)) * 64 + l) * 4])

        // 4 groups: {issue 4 LDS frag reads} {3 register slabs} {consume}
#pragma unroll
        for (int g = 0; g < 4; ++g) {
            f16x8 b0 = WLREAD(4 * g + 0);
            f16x8 b1 = WLREAD(4 * g + 1);
            f16x8 b2 = WLREAD(4 * g + 2);
            f16x8 b3 = WLREAD(4 * g + 3);
#pragma unroll
            for (int s = 3 * g; s < 3 * g + 3; ++s) {
                f16x8 a = ALOAD(s);
                acc0 = __builtin_amdgcn_mfma_f32_16x16x32_f16(a, Wf[0][s], acc0, 0, 0, 0);
                acc1 = __builtin_amdgcn_mfma_f32_16x16x32_f16(a, Wf[1][s], acc1, 0, 0, 0);
                acc2 = __builtin_amdgcn_mfma_f32_16x16x32_f16(a, Wf[2][s], acc2, 0, 0, 0);
                acc3 = __builtin_amdgcn_mfma_f32_16x16x32_f16(a, Wf[3][s], acc3, 0, 0, 0);
            }
            f16x8 a = ALOAD(12 + g);
            acc0 = __builtin_amdgcn_mfma_f32_16x16x32_f16(a, b0, acc0, 0, 0, 0);
            acc1 = __builtin_amdgcn_mfma_f32_16x16x32_f16(a, b1, acc1, 0, 0, 0);
            acc2 = __builtin_amdgcn_mfma_f32_16x16x32_f16(a, b2, acc2, 0, 0, 0);
            acc3 = __builtin_amdgcn_mfma_f32_16x16x32_f16(a, b3, acc3, 0, 0, 0);
        }
#undef ALOAD
#undef WLREAD

        // tail: row 0 of D lives in lanes 0-15, reg .x
        float nv0 = 0.f, nv1 = 0.f, nv2 = 0.f, nv3 = 0.f;
        if (l < 16) {
            float* prow = outb + (size_t)t * (B * U);
            const float* prown = outb + (size_t)((t + 1 < T) ? t + 1 : t) * (B * U);
            f16* hbn = (f16*)hbuf[par ^ 1];

            float h0 = fast_tanh(pv0 + acc0.x);
            float h1 = fast_tanh(pv1 + acc1.x);
            float h2 = fast_tanh(pv2 + acc2.x);
            float h3 = fast_tanh(pv3 + acc3.x);
            prow[64 * w + 0  + lc] = h0;
            prow[64 * w + 16 + lc] = h1;
            prow[64 * w + 32 + lc] = h2;
            prow[64 * w + 48 + lc] = h3;
            hbn[64 * w + 0  + lc] = (f16)h0;
            hbn[64 * w + 16 + lc] = (f16)h1;
            hbn[64 * w + 32 + lc] = (f16)h2;
            hbn[64 * w + 48 + lc] = (f16)h3;

            nv0 = prown[64 * w + 0  + lc];
            nv1 = prown[64 * w + 16 + lc];
            nv2 = prown[64 * w + 32 + lc];
            nv3 = prown[64 * w + 48 + lc];
        }

        __syncthreads();   // h(par^1) visible for next step
        pv0 = nv0; pv1 = nv1; pv2 = nv2; pv3 = nv3;
    }
}

// ---------------------------------------------------------------------------
extern "C" void kernel_launch(void* const* d_in, const int* in_sizes, int n_in,
                              void* d_out, int out_size, void* d_ws, size_t ws_size,
                              hipStream_t stream)
{
    (void)d_ws; (void)ws_size; (void)in_sizes; (void)n_in; (void)out_size;
    const float* x    = (const float*)d_in[0];  // [B, T, D]
    const float* Wx   = (const float*)d_in[1];  // [D, U]
    const float* Wh   = (const float*)d_in[2];  // [U, U]
    const float* bias = (const float*)d_in[3];  // [U]
    float* out = (float*)d_out;                 // [T, B, U]

    pgemm_kernel<<<dim3((T * B) / 128, U / 128), 256, 0, stream>>>(x, Wx, bias, out);
    rnn_kernel<<<B, 512, 0, stream>>>(Wh, out);
}